// Round 9
// baseline (325.706 us; speedup 1.0000x reference)
//
#include <hip/hip_runtime.h>
#include <stdint.h>

typedef unsigned short u16;
typedef __attribute__((ext_vector_type(8))) short bfx8;   // 8 bf16 = 4 VGPR (MFMA A/B frag)
typedef __attribute__((ext_vector_type(4))) float fx4;    // 16x16 MFMA C/D frag
typedef __attribute__((ext_vector_type(16))) float fx16;  // 32x32 MFMA C/D frag

// ---------- helpers ----------
static __device__ __forceinline__ u16 f2b(float f) {
  union { float f; uint32_t u; } v; v.f = f;
  uint32_t r = v.u + 0x7fffu + ((v.u >> 16) & 1u);   // RNE
  return (u16)(r >> 16);
}

static __device__ __forceinline__ uint32_t cvtpk(float lo, float hi) {
  uint32_t r;
  asm("v_cvt_pk_bf16_f32 %0, %1, %2" : "=v"(r) : "v"(lo), "v"(hi));
  return r;
}

static __device__ __forceinline__ float ex2(float x) {   // raw v_exp_f32 (2^x)
  float r;
  asm("v_exp_f32 %0, %1" : "=v"(r) : "v"(x));
  return r;
}

static __device__ __forceinline__ void gload16(const void* g, void* lds) {
  __builtin_amdgcn_global_load_lds((const __attribute__((address_space(1))) uint32_t*)g,
                                   (__attribute__((address_space(3))) uint32_t*)lds,
                                   16, 0, 0);
}

// ---------- f32 -> bf16 convert (8 elems/thread, vectorized) ----------
__global__ __launch_bounds__(256) void f32_to_bf16_k(const float* __restrict__ in,
                                                     u16* __restrict__ out, int n) {
  int i = (blockIdx.x * 256 + threadIdx.x) * 8;
  if (i >= n) return;
  float4 a = *(const float4*)(in + i);
  float4 b = *(const float4*)(in + i + 4);
  bfx8 o;
  o[0]=(short)f2b(a.x); o[1]=(short)f2b(a.y); o[2]=(short)f2b(a.z); o[3]=(short)f2b(a.w);
  o[4]=(short)f2b(b.x); o[5]=(short)f2b(b.y); o[6]=(short)f2b(b.z); o[7]=(short)f2b(b.w);
  *(bfx8*)(out + i) = o;
}

// ---------- 1024x1024 f32 transpose -> bf16 (4 matrices batched in z) ----------
struct TransArgs { const float* in[4]; u16* out[4]; };
__global__ __launch_bounds__(256) void transpose4_k(TransArgs ta) {
  const float* in = ta.in[blockIdx.z];
  u16* out = ta.out[blockIdx.z];
  __shared__ u16 t[64][65];
  const int bx = blockIdx.x * 64, by = blockIdx.y * 64;
  const int tid = threadIdx.x;
#pragma unroll
  for (int i = 0; i < 16; ++i) {
    int idx = tid + i * 256; int r = idx >> 6, c = idx & 63;
    t[c][r] = f2b(in[(size_t)(by + r) * 1024 + bx + c]);
  }
  __syncthreads();
#pragma unroll
  for (int i = 0; i < 16; ++i) {
    int idx = tid + i * 256; int r = idx >> 6, c = idx & 63;
    out[(size_t)(bx + r) * 1024 + by + c] = t[r][c];
  }
}

// ---------- b2[f] = proj_b[f] + sum_e proj_w[f][e]*out_b[e] ----------
__global__ __launch_bounds__(256) void make_b2_k(const float* __restrict__ pw,
                                                 const float* __restrict__ ob,
                                                 const float* __restrict__ pb,
                                                 float* __restrict__ b2) {
  const int f = blockIdx.x, tid = threadIdx.x;
  float s = 0.f;
  for (int e = tid; e < 1024; e += 256) s += pw[(size_t)f * 1024 + e] * ob[e];
#pragma unroll
  for (int d = 1; d < 64; d <<= 1) s += __shfl_xor(s, d);
  __shared__ float red[4];
  if ((tid & 63) == 0) red[tid >> 6] = s;
  __syncthreads();
  if (tid == 0) b2[f] = red[0] + red[1] + red[2] + red[3] + pb[f];
}

// ---------- GEMM core: C = A(MxK) * Bt(NxK)^T, 128x128 tile, BK=64, 4 waves ----------
static __device__ __forceinline__ void gemm_core(const u16* __restrict__ A,
                                                 const u16* __restrict__ Bt,
                                                 int K, int bm, int bn,
                                                 u16* As, u16* Bs, fx4 (&acc)[4][4]) {
  const int tid = threadIdx.x, w = tid >> 6, l = tid & 63, lm = l & 15, lk = l >> 4;
  const int wm = w >> 1, wn = w & 1;
  const int nkt = K >> 6;
  for (int kt = 0; kt < nkt; ++kt) {
#pragma unroll
    for (int i = 0; i < 4; ++i) {
      int off = i * 4096 + w * 1024;         // wave-uniform LDS byte base
      int loff = off + l * 16;               // this lane's byte
      int row = loff >> 7, cb = loff & 127;  // tile row, byte-in-row (BK*2=128B rows)
      gload16((const char*)A + ((size_t)(bm * 128 + row) * K + kt * 64) * 2 + cb,
              (char*)As + off);
      gload16((const char*)Bt + ((size_t)(bn * 128 + row) * K + kt * 64) * 2 + cb,
              (char*)Bs + off);
    }
    __syncthreads();
#pragma unroll
    for (int kk = 0; kk < 2; ++kk) {
      bfx8 a[4], b[4];
#pragma unroll
      for (int mi = 0; mi < 4; ++mi)
        a[mi] = *(const bfx8*)((const char*)As + (wm * 64 + mi * 16 + lm) * 128 + lk * 16 + kk * 64);
#pragma unroll
      for (int nj = 0; nj < 4; ++nj)
        b[nj] = *(const bfx8*)((const char*)Bs + (wn * 64 + nj * 16 + lm) * 128 + lk * 16 + kk * 64);
#pragma unroll
      for (int mi = 0; mi < 4; ++mi)
#pragma unroll
        for (int nj = 0; nj < 4; ++nj)
          acc[mi][nj] = __builtin_amdgcn_mfma_f32_16x16x32_bf16(a[mi], b[nj], acc[mi][nj], 0, 0, 0);
    }
    __syncthreads();
  }
}

// ---------- combine GEMMs (4 batched in z): C[f][d] = sum_e A[f][e]*Bt[d][e], bf16 out ----------
struct CombArgs { const u16* A[4]; const u16* Bt[4]; u16* C[4]; };
__global__ __launch_bounds__(256) void gemm_combine_k(CombArgs ca) {
  const int z = blockIdx.z;
  __shared__ u16 As[8192], Bs[8192];
  fx4 acc[4][4];
#pragma unroll
  for (int mi = 0; mi < 4; ++mi)
#pragma unroll
    for (int nj = 0; nj < 4; ++nj) acc[mi][nj] = 0.f;
  gemm_core(ca.A[z], ca.Bt[z], 1024, blockIdx.x, blockIdx.y, As, Bs, acc);
  const int tid = threadIdx.x, w = tid >> 6, l = tid & 63, lm = l & 15, lk = l >> 4;
  const int wm = w >> 1, wn = w & 1;
  u16* C = ca.C[z];
#pragma unroll
  for (int mi = 0; mi < 4; ++mi)
#pragma unroll
    for (int nj = 0; nj < 4; ++nj)
#pragma unroll
      for (int r = 0; r < 4; ++r) {
        int m = blockIdx.x * 128 + wm * 64 + mi * 16 + lk * 4 + r;
        int n = blockIdx.y * 128 + wn * 64 + nj * 16 + lm;
        C[(size_t)m * 1024 + n] = f2b(acc[mi][nj][r]);
      }
}

// ---------- QKV GEMM: [8192x1024]x[3072x1024]^T + in_b ----------
// Q -> (B,H,S,64) plain; K -> (B,H,S,64) with hd XOR-swizzled (attn LDS swizzle baked in);
// V -> per-(bh,ktile) TRANSPOSED tile Vt[64 d][64 k], row-XOR-swizzled (same pattern as K).
__global__ __launch_bounds__(256) void gemm_qkv_k(const u16* __restrict__ xb,
                                                  const u16* __restrict__ Wc,
                                                  const float* __restrict__ bias,
                                                  u16* __restrict__ Qh, u16* __restrict__ Kh,
                                                  u16* __restrict__ Vh) {
  __shared__ u16 As[8192], Bs[8192];
  fx4 acc[4][4];
#pragma unroll
  for (int mi = 0; mi < 4; ++mi)
#pragma unroll
    for (int nj = 0; nj < 4; ++nj) acc[mi][nj] = 0.f;
  gemm_core(xb, Wc, 1024, blockIdx.x, blockIdx.y, As, Bs, acc);
  const int tid = threadIdx.x, w = tid >> 6, l = tid & 63, lm = l & 15, lk = l >> 4;
  const int wm = w >> 1, wn = w & 1;
  const int t = (blockIdx.y * 128) >> 10;                    // tensor select (tile-uniform)
  u16* dst = (t == 0) ? Qh : ((t == 1) ? Kh : Vh);
#pragma unroll
  for (int mi = 0; mi < 4; ++mi)
#pragma unroll
    for (int nj = 0; nj < 4; ++nj)
#pragma unroll
      for (int r = 0; r < 4; ++r) {
        int m = blockIdx.x * 128 + wm * 64 + mi * 16 + lk * 4 + r;
        int n = blockIdx.y * 128 + wn * 64 + nj * 16 + lm;
        float v = acc[mi][nj][r] + bias[n];
        int f = n & 1023, h = f >> 6, hd = f & 63, b = m >> 11, s = m & 2047;
        size_t hb = ((size_t)(b * 16 + h)) * 131072;   // 2048*64
        size_t idx;
        if (t == 2) {
          int sl = s & 63, st = s >> 6;                // Vt[d=hd][k=sl], row-swizzled
          idx = hb + (size_t)st * 4096 + (size_t)(hd * 64 + (sl ^ ((hd & 7) << 3)));
        } else if (t == 1) {
          idx = hb + (size_t)s * 64 + (hd ^ ((s & 7) << 3));
        } else {
          idx = hb + (size_t)s * 64 + hd;
        }
        dst[idx] = f2b(v);
      }
}

// ---------- final GEMM: ctx[8192x1024] x W2[1024x1024]^T + b2 + x, f32 out ----------
__global__ __launch_bounds__(256) void gemm_final_k(const u16* __restrict__ ctx,
                                                    const u16* __restrict__ W2,
                                                    const float* __restrict__ b2,
                                                    const float* __restrict__ x,
                                                    float* __restrict__ out) {
  __shared__ u16 As[8192], Bs[8192];
  fx4 acc[4][4];
#pragma unroll
  for (int mi = 0; mi < 4; ++mi)
#pragma unroll
    for (int nj = 0; nj < 4; ++nj) acc[mi][nj] = 0.f;
  gemm_core(ctx, W2, 1024, blockIdx.x, blockIdx.y, As, Bs, acc);
  const int tid = threadIdx.x, w = tid >> 6, l = tid & 63, lm = l & 15, lk = l >> 4;
  const int wm = w >> 1, wn = w & 1;
#pragma unroll
  for (int mi = 0; mi < 4; ++mi)
#pragma unroll
    for (int nj = 0; nj < 4; ++nj)
#pragma unroll
      for (int r = 0; r < 4; ++r) {
        int m = blockIdx.x * 128 + wm * 64 + mi * 16 + lk * 4 + r;
        int n = blockIdx.y * 128 + wn * 64 + nj * 16 + lm;
        size_t idx = (size_t)m * 1024 + n;
        out[idx] = acc[mi][nj][r] + b2[n] + x[idx];
      }
}

// ---------- fused attention, 32x32-MFMA path, 64 q-rows per wave ----------
// scores = QK^T/8 + tril(1.0), softmax over FULL row (log2 domain), ctx = P*V.
// 4 waves (256 thr), QBLK=256: each wave owns 64 q rows (2 subtiles of 32);
// lane owns q = qb + j*32 + (l&31), key-half h = l>>5.
// DS-bound regime fix: K/V fragment reads shared across both subtiles ->
// DS bytes per unit work halved vs 32q/wave. VGPR-capped at 2 waves/SIMD.
__global__ __launch_bounds__(256, 2) void attn_k(const u16* __restrict__ Qh,
                                                 const u16* __restrict__ Kh,
                                                 const u16* __restrict__ Vh,
                                                 u16* __restrict__ ctx) {
  // XCD-chunked swizzle: 512 blocks / 8 XCDs = 64 contiguous work items (8 bh) per XCD.
  const int bl = blockIdx.x;
  const int wk = (bl & 7) * 64 + (bl >> 3);
  const int bh = wk >> 3, qt = wk & 7;
  const int tid = threadIdx.x, w = tid >> 6, l = tid & 63;
  const int ql = l & 31, h = l >> 5;
  __shared__ __align__(16) u16 Ks[2][4096];
  __shared__ __align__(16) u16 Vs[2][4096];

  const float SC = 0.18033688011112042f;    // 0.125 * log2(e)
  const float MA = 1.4426950408889634f;     // 1.0  * log2(e)
  const float THR = 11.541560327111708f;    // 8.0  * log2(e)

  const size_t base = (size_t)bh * 131072;
  const int qb = qt * 256 + w * 64;         // wave q-base (64-aligned)
  // Q B-frags for both subtiles: lane holds Q[qb+j*32+ql][d = ks*16 + 8h + e]
  bfx8 qf[2][4];
#pragma unroll
  for (int j = 0; j < 2; ++j) {
    const u16* qp = Qh + base + (size_t)(qb + j * 32 + ql) * 64 + 8 * h;
    qf[j][0] = *(const bfx8*)(qp);
    qf[j][1] = *(const bfx8*)(qp + 16);
    qf[j][2] = *(const bfx8*)(qp + 32);
    qf[j][3] = *(const bfx8*)(qp + 48);
  }
  float m_run[2] = {-1024.f, -1024.f};
  float l_part[2] = {0.f, 0.f};
  fx16 accO[2][2];                          // [subtile][d-half]
  accO[0][0] = 0.f; accO[0][1] = 0.f; accO[1][0] = 0.f; accO[1][1] = 0.f;

  const char* Kg = (const char*)(Kh + base);
  const char* Vg = (const char*)(Vh + base);
  const int o = tid * 16;                   // 256 thr x 16B = half a tile per instr
  const int sw8 = (ql & 7) << 4;

#define STAGE(t, s)                                                        \
  {                                                                        \
    gload16(Kg + (size_t)(t) * 8192 + o,        (char*)Ks[s] + o);         \
    gload16(Kg + (size_t)(t) * 8192 + o + 4096, (char*)Ks[s] + o + 4096);  \
    gload16(Vg + (size_t)(t) * 8192 + o,        (char*)Vs[s] + o);         \
    gload16(Vg + (size_t)(t) * 8192 + o + 4096, (char*)Vs[s] + o + 4096);  \
  }

  STAGE(0, 0);
  asm volatile("s_waitcnt vmcnt(0)" ::: "memory");
  __builtin_amdgcn_s_barrier();
  __builtin_amdgcn_sched_barrier(0);

  int cur = 0;
  for (int kt = 0; kt < 32; ++kt) {
    if (kt + 1 < 32) STAGE(kt + 1, cur ^ 1);   // issue early; lands before end-of-iter wait
    __builtin_amdgcn_sched_barrier(0);

    const char* Kc = (const char*)Ks[cur];
    const char* Vc = (const char*)Vs[cur];

    // QK^T (swapped): K-frags read ONCE, used by both subtiles (DS halved per work)
    fx16 sS[2][2];                          // [subtile][key-block]
    sS[0][0] = 0.f; sS[0][1] = 0.f; sS[1][0] = 0.f; sS[1][1] = 0.f;
    __builtin_amdgcn_s_setprio(1);
#pragma unroll
    for (int ks = 0; ks < 4; ++ks) {
      bfx8 kf0 = *(const bfx8*)(Kc + (0 * 32 + ql) * 128 + (((ks << 5) | (h << 4)) ^ sw8));
      bfx8 kf1 = *(const bfx8*)(Kc + (1 * 32 + ql) * 128 + (((ks << 5) | (h << 4)) ^ sw8));
      sS[0][0] = __builtin_amdgcn_mfma_f32_32x32x16_bf16(kf0, qf[0][ks], sS[0][0], 0, 0, 0);
      sS[1][0] = __builtin_amdgcn_mfma_f32_32x32x16_bf16(kf0, qf[1][ks], sS[1][0], 0, 0, 0);
      sS[0][1] = __builtin_amdgcn_mfma_f32_32x32x16_bf16(kf1, qf[0][ks], sS[0][1], 0, 0, 0);
      sS[1][1] = __builtin_amdgcn_mfma_f32_32x32x16_bf16(kf1, qf[1][ks], sS[1][1], 0, 0, 0);
    }
    __builtin_amdgcn_s_setprio(0);

    // softmax per subtile (log2 domain, bias-folded, defer-max; one joint ballot)
    const int dk = kt - (qb >> 6);          // qb 64-aligned -> single dk for both subtiles
    float full[2];
#pragma unroll
    for (int j = 0; j < 2; ++j) {
      const int qj = qb + j * 32 + ql;
      float cO = -m_run[j], cI = cO + MA;
      if (dk < 0) {
#pragma unroll
        for (int r = 0; r < 16; ++r) {
          sS[j][0][r] = fmaf(sS[j][0][r], SC, cI);
          sS[j][1][r] = fmaf(sS[j][1][r], SC, cI);
        }
      } else if (dk > 0) {
#pragma unroll
        for (int r = 0; r < 16; ++r) {
          sS[j][0][r] = fmaf(sS[j][0][r], SC, cO);
          sS[j][1][r] = fmaf(sS[j][1][r], SC, cO);
        }
      } else {
#pragma unroll
        for (int kb = 0; kb < 2; ++kb)
#pragma unroll
          for (int r = 0; r < 16; ++r) {
            int key = kt * 64 + kb * 32 + (r & 3) + 8 * (r >> 2) + 4 * h;
            sS[j][kb][r] = fmaf(sS[j][kb][r], SC, (key <= qj) ? cI : cO);
          }
      }
      float m0 = fmaxf(fmaxf(sS[j][0][0], sS[j][0][1]), fmaxf(sS[j][0][2], sS[j][0][3]));
      float m1 = fmaxf(fmaxf(sS[j][0][4], sS[j][0][5]), fmaxf(sS[j][0][6], sS[j][0][7]));
      float m2 = fmaxf(fmaxf(sS[j][0][8], sS[j][0][9]), fmaxf(sS[j][0][10], sS[j][0][11]));
      float m3 = fmaxf(fmaxf(sS[j][0][12], sS[j][0][13]), fmaxf(sS[j][0][14], sS[j][0][15]));
      float m4 = fmaxf(fmaxf(sS[j][1][0], sS[j][1][1]), fmaxf(sS[j][1][2], sS[j][1][3]));
      float m5 = fmaxf(fmaxf(sS[j][1][4], sS[j][1][5]), fmaxf(sS[j][1][6], sS[j][1][7]));
      float m6 = fmaxf(fmaxf(sS[j][1][8], sS[j][1][9]), fmaxf(sS[j][1][10], sS[j][1][11]));
      float m7 = fmaxf(fmaxf(sS[j][1][12], sS[j][1][13]), fmaxf(sS[j][1][14], sS[j][1][15]));
      float mx = fmaxf(fmaxf(fmaxf(m0, m1), fmaxf(m2, m3)), fmaxf(fmaxf(m4, m5), fmaxf(m6, m7)));
      full[j] = fmaxf(mx, __shfl_xor(mx, 32));
    }
    if (!__all(fmaxf(full[0], full[1]) <= THR)) {   // rare rescale (d=0 -> no-op per subtile)
#pragma unroll
      for (int j = 0; j < 2; ++j) {
        float d = fmaxf(full[j], 0.f);
        float corr = ex2(-d);
        m_run[j] += d;
        l_part[j] *= corr;
#pragma unroll
        for (int r = 0; r < 16; ++r) {
          int rq = (r & 3) + 8 * (r >> 2) + 4 * h;
          float cr = __shfl(corr, (l & 32) | rq);
          accO[j][0][r] *= cr;
          accO[j][1][r] *= cr;
          sS[j][0][r] -= d;
          sS[j][1][r] -= d;
        }
      }
    }
    // exp + partial row-sums + P->bf16 + cross-half exchange, per subtile
    uint32_t pw[2][8][2];
#pragma unroll
    for (int j = 0; j < 2; ++j) {
      fx16 tt;
#pragma unroll
      for (int r = 0; r < 16; ++r) {
        sS[j][0][r] = ex2(sS[j][0][r]);
        sS[j][1][r] = ex2(sS[j][1][r]);
        tt[r] = sS[j][0][r] + sS[j][1][r];
      }
      float ls0 = tt[0] + tt[8],  ls1 = tt[1] + tt[9];
      float ls2 = tt[2] + tt[10], ls3 = tt[3] + tt[11];
      float ls4 = tt[4] + tt[12], ls5 = tt[5] + tt[13];
      float ls6 = tt[6] + tt[14], ls7 = tt[7] + tt[15];
      l_part[j] += ((ls0 + ls4) + (ls1 + ls5)) + ((ls2 + ls6) + (ls3 + ls7));
#pragma unroll
      for (int kb = 0; kb < 2; ++kb)
#pragma unroll
        for (int gg = 0; gg < 4; ++gg) {
          pw[j][kb * 4 + gg][0] = cvtpk(sS[j][kb][4 * gg + 0], sS[j][kb][4 * gg + 1]);
          pw[j][kb * 4 + gg][1] = cvtpk(sS[j][kb][4 * gg + 2], sS[j][kb][4 * gg + 3]);
        }
    }

    // PV: V-frags read ONCE, used by both subtiles; pa via xor-32 exchange (round-8 verified)
    __builtin_amdgcn_s_setprio(1);
#pragma unroll
    for (int ks = 0; ks < 4; ++ks) {
      bfx8 vf0 = *(const bfx8*)(Vc + (0 * 32 + ql) * 128 + (((ks << 5) | (h << 4)) ^ sw8));
      bfx8 vf1 = *(const bfx8*)(Vc + (1 * 32 + ql) * 128 + (((ks << 5) | (h << 4)) ^ sw8));
#pragma unroll
      for (int j = 0; j < 2; ++j) {
        union { uint32_t u[4]; bfx8 v; } pa;
#pragma unroll
        for (int p = 0; p < 2; ++p) {
          uint32_t contrib = h ? pw[j][2 * ks][p] : pw[j][2 * ks + 1][p];
          uint32_t rcv = __shfl_xor(contrib, 32);
          pa.u[p]     = h ? rcv : pw[j][2 * ks][p];
          pa.u[2 + p] = h ? pw[j][2 * ks + 1][p] : rcv;
        }
        accO[j][0] = __builtin_amdgcn_mfma_f32_32x32x16_bf16(pa.v, vf0, accO[j][0], 0, 0, 0);
        accO[j][1] = __builtin_amdgcn_mfma_f32_32x32x16_bf16(pa.v, vf1, accO[j][1], 0, 0, 0);
      }
    }
    __builtin_amdgcn_s_setprio(0);

    asm volatile("s_waitcnt vmcnt(0)" ::: "memory");   // next tile landed (in flight all iter)
    __builtin_amdgcn_s_barrier();
    __builtin_amdgcn_sched_barrier(0);
    cur ^= 1;
  }
#undef STAGE

  // epilogue: pair-reduce l, write ctx (B,S,D) bf16
  const int b = bh >> 4, hcol = bh & 15;
#pragma unroll
  for (int j = 0; j < 2; ++j) {
    float inv = 1.0f / (l_part[j] + __shfl_xor(l_part[j], 32));
#pragma unroll
    for (int r = 0; r < 16; ++r) {
      int rq = (r & 3) + 8 * (r >> 2) + 4 * h;
      float invq = __shfl(inv, (l & 32) | rq);
      size_t rowb = ((size_t)b * 2048 + (qb + j * 32 + rq)) * 1024 + hcol * 64 + ql;
      ctx[rowb]      = f2b(accO[j][0][r] * invq);   // d = ql
      ctx[rowb + 32] = f2b(accO[j][1][r] * invq);   // d = 32 + ql
    }
  }
}

// ---------- launch ----------
extern "C" void kernel_launch(void* const* d_in, const int* in_sizes, int n_in,
                              void* d_out, int out_size, void* d_ws, size_t ws_size,
                              hipStream_t stream) {
  (void)in_sizes; (void)n_in; (void)out_size; (void)ws_size;
  const float* x      = (const float*)d_in[0];
  const float* Wq     = (const float*)d_in[1];
  const float* Wk     = (const float*)d_in[2];
  const float* Wv     = (const float*)d_in[3];
  const float* in_w   = (const float*)d_in[4];
  const float* in_b   = (const float*)d_in[5];
  const float* out_w  = (const float*)d_in[6];
  const float* out_b  = (const float*)d_in[7];
  const float* proj_w = (const float*)d_in[8];
  const float* proj_b = (const float*)d_in[9];
  float* out = (float*)d_out;

  char* ws = (char*)d_ws;
  const size_t MB = 1ull << 20;
  // lifetime-overlapped layout (72 MB + 4 KB total):
  u16* xb   = (u16*)(ws);                    // 16MB; dead after QKV GEMM -> reused as ctx
  u16* ctx  = xb;
  u16* Qh   = (u16*)(ws + 16 * MB);          // 16MB
  u16* Kh   = (u16*)(ws + 32 * MB);          // 16MB; first 6MB doubles as in_w bf16 (prep only)
  u16* Vh   = (u16*)(ws + 48 * MB);          // 16MB; first 8MB = tmpT, +2MB = proj_w bf16 (prep only)
  u16* inwb = Kh;
  u16* tmpT = Vh;
  u16* pwb  = (u16*)(ws + 48 * MB + 8 * MB);
  u16* Wc   = (u16*)(ws + 64 * MB);          // 6MB combined QKV weights
  u16* W2   = (u16*)(ws + 70 * MB);          // 2MB combined output weights
  float* b2 = (float*)(ws + 72 * MB);        // 4KB combined output bias

  f32_to_bf16_k<<<4096, 256, 0, stream>>>(x, xb, 8388608);
  f32_to_bf16_k<<<1536, 256, 0, stream>>>(in_w, inwb, 3145728);
  f32_to_bf16_k<<<512, 256, 0, stream>>>(proj_w, pwb, 1048576);

  TransArgs ta;
  ta.in[0] = Wq; ta.in[1] = Wk; ta.in[2] = Wv; ta.in[3] = out_w;
  for (int z = 0; z < 4; ++z) ta.out[z] = tmpT + (size_t)z * 1048576;
  transpose4_k<<<dim3(16, 16, 4), 256, 0, stream>>>(ta);

  CombArgs ca;
  ca.A[0] = inwb; ca.A[1] = inwb + 1048576; ca.A[2] = inwb + 2097152; ca.A[3] = pwb;
  for (int z = 0; z < 4; ++z) ca.Bt[z] = tmpT + (size_t)z * 1048576;
  ca.C[0] = Wc; ca.C[1] = Wc + 1048576; ca.C[2] = Wc + 2097152; ca.C[3] = W2;
  gemm_combine_k<<<dim3(8, 8, 4), 256, 0, stream>>>(ca);

  make_b2_k<<<1024, 256, 0, stream>>>(proj_w, out_b, proj_b, b2);

  gemm_qkv_k<<<dim3(64, 24), 256, 0, stream>>>(xb, Wc, in_b, Qh, Kh, Vh);
  attn_k<<<512, 256, 0, stream>>>(Qh, Kh, Vh, ctx);
  gemm_final_k<<<dim3(64, 8), 256, 0, stream>>>(ctx, W2, b2, x, out);
}

// Round 10
// 316.778 us; speedup vs baseline: 1.0282x; 1.0282x over previous
//
#include <hip/hip_runtime.h>
#include <stdint.h>

typedef unsigned short u16;
typedef __attribute__((ext_vector_type(8))) short bfx8;   // 8 bf16 = 4 VGPR (MFMA A/B frag)
typedef __attribute__((ext_vector_type(4))) float fx4;    // 16x16 MFMA C/D frag
typedef __attribute__((ext_vector_type(16))) float fx16;  // 32x32 MFMA C/D frag

static constexpr float SCc  = 0.18033688011112042f;   // 0.125 * log2(e)
static constexpr float MAc  = 1.4426950408889634f;    // 1.0   * log2(e)
static constexpr float THRc = 11.541560327111708f;    // 8.0   * log2(e)

// ---------- helpers ----------
static __device__ __forceinline__ u16 f2b(float f) {
  union { float f; uint32_t u; } v; v.f = f;
  uint32_t r = v.u + 0x7fffu + ((v.u >> 16) & 1u);   // RNE
  return (u16)(r >> 16);
}

static __device__ __forceinline__ uint32_t cvtpk(float lo, float hi) {
  uint32_t r;
  asm("v_cvt_pk_bf16_f32 %0, %1, %2" : "=v"(r) : "v"(lo), "v"(hi));
  return r;
}

static __device__ __forceinline__ float ex2(float x) {   // raw v_exp_f32 (2^x)
  float r;
  asm("v_exp_f32 %0, %1" : "=v"(r) : "v"(x));
  return r;
}

static __device__ __forceinline__ void gload16(const void* g, void* lds) {
  __builtin_amdgcn_global_load_lds((const __attribute__((address_space(1))) uint32_t*)g,
                                   (__attribute__((address_space(3))) uint32_t*)lds,
                                   16, 0, 0);
}

// ---------- attn softmax helpers (all inlined at distinct call sites -> static regs) ----------
static __device__ __forceinline__ void mask_tile(fx16& s, int dk, int kbase4h, int qj,
                                                 float cO, float cI) {
  if (dk < 0) {
#pragma unroll
    for (int r = 0; r < 16; ++r) s[r] = fmaf(s[r], SCc, cI);
  } else if (dk > 0) {
#pragma unroll
    for (int r = 0; r < 16; ++r) s[r] = fmaf(s[r], SCc, cO);
  } else {
#pragma unroll
    for (int r = 0; r < 16; ++r) {
      int key = kbase4h + (r & 3) + 8 * (r >> 2);
      s[r] = fmaf(s[r], SCc, (key <= qj) ? cI : cO);
    }
  }
}

static __device__ __forceinline__ float vmax32(const fx16& a, const fx16& b) {
  float m0 = fmaxf(fmaxf(a[0], a[1]), fmaxf(a[2], a[3]));
  float m1 = fmaxf(fmaxf(a[4], a[5]), fmaxf(a[6], a[7]));
  float m2 = fmaxf(fmaxf(a[8], a[9]), fmaxf(a[10], a[11]));
  float m3 = fmaxf(fmaxf(a[12], a[13]), fmaxf(a[14], a[15]));
  float m4 = fmaxf(fmaxf(b[0], b[1]), fmaxf(b[2], b[3]));
  float m5 = fmaxf(fmaxf(b[4], b[5]), fmaxf(b[6], b[7]));
  float m6 = fmaxf(fmaxf(b[8], b[9]), fmaxf(b[10], b[11]));
  float m7 = fmaxf(fmaxf(b[12], b[13]), fmaxf(b[14], b[15]));
  return fmaxf(fmaxf(fmaxf(m0, m1), fmaxf(m2, m3)), fmaxf(fmaxf(m4, m5), fmaxf(m6, m7)));
}

static __device__ __forceinline__ void rescale32(fx16& o0, fx16& o1, fx16& s0, fx16& s1,
                                                 float d, float corr, int lane, int h) {
#pragma unroll
  for (int r = 0; r < 16; ++r) {
    int rq = (r & 3) + 8 * (r >> 2) + 4 * h;
    float cr = __shfl(corr, (lane & 32) | rq);
    o0[r] *= cr; o1[r] *= cr; s0[r] -= d; s1[r] -= d;
  }
}

static __device__ __forceinline__ float expsum32(fx16& s0, fx16& s1) {
  fx16 tt;
#pragma unroll
  for (int r = 0; r < 16; ++r) { s0[r] = ex2(s0[r]); s1[r] = ex2(s1[r]); tt[r] = s0[r] + s1[r]; }
  float a0 = tt[0] + tt[8],  a1 = tt[1] + tt[9];
  float a2 = tt[2] + tt[10], a3 = tt[3] + tt[11];
  float a4 = tt[4] + tt[12], a5 = tt[5] + tt[13];
  float a6 = tt[6] + tt[14], a7 = tt[7] + tt[15];
  return ((a0 + a4) + (a1 + a5)) + ((a2 + a6) + (a3 + a7));
}

static __device__ __forceinline__ void pack32(const fx16& s0, const fx16& s1,
                                              uint32_t (&pw)[8][2]) {
#pragma unroll
  for (int gg = 0; gg < 4; ++gg) {
    pw[gg][0]     = cvtpk(s0[4 * gg + 0], s0[4 * gg + 1]);
    pw[gg][1]     = cvtpk(s0[4 * gg + 2], s0[4 * gg + 3]);
    pw[4 + gg][0] = cvtpk(s1[4 * gg + 0], s1[4 * gg + 1]);
    pw[4 + gg][1] = cvtpk(s1[4 * gg + 2], s1[4 * gg + 3]);
  }
}

static __device__ __forceinline__ bfx8 mk_pa(const uint32_t (&pw)[8][2], int ks, int h) {
  union { uint32_t u[4]; bfx8 v; } pa;
#pragma unroll
  for (int p = 0; p < 2; ++p) {
    uint32_t contrib = h ? pw[2 * ks][p] : pw[2 * ks + 1][p];
    uint32_t rcv = __shfl_xor(contrib, 32);
    pa.u[p]     = h ? rcv : pw[2 * ks][p];
    pa.u[2 + p] = h ? pw[2 * ks + 1][p] : rcv;
  }
  return pa.v;
}

// ---------- f32 -> bf16 convert (8 elems/thread, vectorized) ----------
__global__ __launch_bounds__(256) void f32_to_bf16_k(const float* __restrict__ in,
                                                     u16* __restrict__ out, int n) {
  int i = (blockIdx.x * 256 + threadIdx.x) * 8;
  if (i >= n) return;
  float4 a = *(const float4*)(in + i);
  float4 b = *(const float4*)(in + i + 4);
  bfx8 o;
  o[0]=(short)f2b(a.x); o[1]=(short)f2b(a.y); o[2]=(short)f2b(a.z); o[3]=(short)f2b(a.w);
  o[4]=(short)f2b(b.x); o[5]=(short)f2b(b.y); o[6]=(short)f2b(b.z); o[7]=(short)f2b(b.w);
  *(bfx8*)(out + i) = o;
}

// ---------- 1024x1024 f32 transpose -> bf16 (4 matrices batched in z) ----------
struct TransArgs { const float* in[4]; u16* out[4]; };
__global__ __launch_bounds__(256) void transpose4_k(TransArgs ta) {
  const float* in = ta.in[blockIdx.z];
  u16* out = ta.out[blockIdx.z];
  __shared__ u16 t[64][65];
  const int bx = blockIdx.x * 64, by = blockIdx.y * 64;
  const int tid = threadIdx.x;
#pragma unroll
  for (int i = 0; i < 16; ++i) {
    int idx = tid + i * 256; int r = idx >> 6, c = idx & 63;
    t[c][r] = f2b(in[(size_t)(by + r) * 1024 + bx + c]);
  }
  __syncthreads();
#pragma unroll
  for (int i = 0; i < 16; ++i) {
    int idx = tid + i * 256; int r = idx >> 6, c = idx & 63;
    out[(size_t)(bx + r) * 1024 + by + c] = t[r][c];
  }
}

// ---------- b2[f] = proj_b[f] + sum_e proj_w[f][e]*out_b[e] ----------
__global__ __launch_bounds__(256) void make_b2_k(const float* __restrict__ pw,
                                                 const float* __restrict__ ob,
                                                 const float* __restrict__ pb,
                                                 float* __restrict__ b2) {
  const int f = blockIdx.x, tid = threadIdx.x;
  float s = 0.f;
  for (int e = tid; e < 1024; e += 256) s += pw[(size_t)f * 1024 + e] * ob[e];
#pragma unroll
  for (int d = 1; d < 64; d <<= 1) s += __shfl_xor(s, d);
  __shared__ float red[4];
  if ((tid & 63) == 0) red[tid >> 6] = s;
  __syncthreads();
  if (tid == 0) b2[f] = red[0] + red[1] + red[2] + red[3] + pb[f];
}

// ---------- GEMM core: C = A(MxK) * Bt(NxK)^T, 128x128 tile, BK=64, 4 waves ----------
static __device__ __forceinline__ void gemm_core(const u16* __restrict__ A,
                                                 const u16* __restrict__ Bt,
                                                 int K, int bm, int bn,
                                                 u16* As, u16* Bs, fx4 (&acc)[4][4]) {
  const int tid = threadIdx.x, w = tid >> 6, l = tid & 63, lm = l & 15, lk = l >> 4;
  const int wm = w >> 1, wn = w & 1;
  const int nkt = K >> 6;
  for (int kt = 0; kt < nkt; ++kt) {
#pragma unroll
    for (int i = 0; i < 4; ++i) {
      int off = i * 4096 + w * 1024;         // wave-uniform LDS byte base
      int loff = off + l * 16;               // this lane's byte
      int row = loff >> 7, cb = loff & 127;  // tile row, byte-in-row (BK*2=128B rows)
      gload16((const char*)A + ((size_t)(bm * 128 + row) * K + kt * 64) * 2 + cb,
              (char*)As + off);
      gload16((const char*)Bt + ((size_t)(bn * 128 + row) * K + kt * 64) * 2 + cb,
              (char*)Bs + off);
    }
    __syncthreads();
#pragma unroll
    for (int kk = 0; kk < 2; ++kk) {
      bfx8 a[4], b[4];
#pragma unroll
      for (int mi = 0; mi < 4; ++mi)
        a[mi] = *(const bfx8*)((const char*)As + (wm * 64 + mi * 16 + lm) * 128 + lk * 16 + kk * 64);
#pragma unroll
      for (int nj = 0; nj < 4; ++nj)
        b[nj] = *(const bfx8*)((const char*)Bs + (wn * 64 + nj * 16 + lm) * 128 + lk * 16 + kk * 64);
#pragma unroll
      for (int mi = 0; mi < 4; ++mi)
#pragma unroll
        for (int nj = 0; nj < 4; ++nj)
          acc[mi][nj] = __builtin_amdgcn_mfma_f32_16x16x32_bf16(a[mi], b[nj], acc[mi][nj], 0, 0, 0);
    }
    __syncthreads();
  }
}

// ---------- combine GEMMs (4 batched in z): C[f][d] = sum_e A[f][e]*Bt[d][e], bf16 out ----------
struct CombArgs { const u16* A[4]; const u16* Bt[4]; u16* C[4]; };
__global__ __launch_bounds__(256) void gemm_combine_k(CombArgs ca) {
  const int z = blockIdx.z;
  __shared__ u16 As[8192], Bs[8192];
  fx4 acc[4][4];
#pragma unroll
  for (int mi = 0; mi < 4; ++mi)
#pragma unroll
    for (int nj = 0; nj < 4; ++nj) acc[mi][nj] = 0.f;
  gemm_core(ca.A[z], ca.Bt[z], 1024, blockIdx.x, blockIdx.y, As, Bs, acc);
  const int tid = threadIdx.x, w = tid >> 6, l = tid & 63, lm = l & 15, lk = l >> 4;
  const int wm = w >> 1, wn = w & 1;
  u16* C = ca.C[z];
#pragma unroll
  for (int mi = 0; mi < 4; ++mi)
#pragma unroll
    for (int nj = 0; nj < 4; ++nj)
#pragma unroll
      for (int r = 0; r < 4; ++r) {
        int m = blockIdx.x * 128 + wm * 64 + mi * 16 + lk * 4 + r;
        int n = blockIdx.y * 128 + wn * 64 + nj * 16 + lm;
        C[(size_t)m * 1024 + n] = f2b(acc[mi][nj][r]);
      }
}

// ---------- QKV GEMM: [8192x1024]x[3072x1024]^T + in_b ----------
// Q -> (B,H,S,64) plain; K -> (B,H,S,64) with hd XOR-swizzled (attn LDS swizzle baked in);
// V -> per-(bh,ktile) TRANSPOSED tile Vt[64 d][64 k], row-XOR-swizzled (same pattern as K).
__global__ __launch_bounds__(256) void gemm_qkv_k(const u16* __restrict__ xb,
                                                  const u16* __restrict__ Wc,
                                                  const float* __restrict__ bias,
                                                  u16* __restrict__ Qh, u16* __restrict__ Kh,
                                                  u16* __restrict__ Vh) {
  __shared__ u16 As[8192], Bs[8192];
  fx4 acc[4][4];
#pragma unroll
  for (int mi = 0; mi < 4; ++mi)
#pragma unroll
    for (int nj = 0; nj < 4; ++nj) acc[mi][nj] = 0.f;
  gemm_core(xb, Wc, 1024, blockIdx.x, blockIdx.y, As, Bs, acc);
  const int tid = threadIdx.x, w = tid >> 6, l = tid & 63, lm = l & 15, lk = l >> 4;
  const int wm = w >> 1, wn = w & 1;
  const int t = (blockIdx.y * 128) >> 10;                    // tensor select (tile-uniform)
  u16* dst = (t == 0) ? Qh : ((t == 1) ? Kh : Vh);
#pragma unroll
  for (int mi = 0; mi < 4; ++mi)
#pragma unroll
    for (int nj = 0; nj < 4; ++nj)
#pragma unroll
      for (int r = 0; r < 4; ++r) {
        int m = blockIdx.x * 128 + wm * 64 + mi * 16 + lk * 4 + r;
        int n = blockIdx.y * 128 + wn * 64 + nj * 16 + lm;
        float v = acc[mi][nj][r] + bias[n];
        int f = n & 1023, h = f >> 6, hd = f & 63, b = m >> 11, s = m & 2047;
        size_t hb = ((size_t)(b * 16 + h)) * 131072;   // 2048*64
        size_t idx;
        if (t == 2) {
          int sl = s & 63, st = s >> 6;                // Vt[d=hd][k=sl], row-swizzled
          idx = hb + (size_t)st * 4096 + (size_t)(hd * 64 + (sl ^ ((hd & 7) << 3)));
        } else if (t == 1) {
          idx = hb + (size_t)s * 64 + (hd ^ ((s & 7) << 3));
        } else {
          idx = hb + (size_t)s * 64 + hd;
        }
        dst[idx] = f2b(v);
      }
}

// ---------- final GEMM: ctx[8192x1024] x W2[1024x1024]^T + b2 + x, f32 out ----------
__global__ __launch_bounds__(256) void gemm_final_k(const u16* __restrict__ ctx,
                                                    const u16* __restrict__ W2,
                                                    const float* __restrict__ b2,
                                                    const float* __restrict__ x,
                                                    float* __restrict__ out) {
  __shared__ u16 As[8192], Bs[8192];
  fx4 acc[4][4];
#pragma unroll
  for (int mi = 0; mi < 4; ++mi)
#pragma unroll
    for (int nj = 0; nj < 4; ++nj) acc[mi][nj] = 0.f;
  gemm_core(ctx, W2, 1024, blockIdx.x, blockIdx.y, As, Bs, acc);
  const int tid = threadIdx.x, w = tid >> 6, l = tid & 63, lm = l & 15, lk = l >> 4;
  const int wm = w >> 1, wn = w & 1;
#pragma unroll
  for (int mi = 0; mi < 4; ++mi)
#pragma unroll
    for (int nj = 0; nj < 4; ++nj)
#pragma unroll
      for (int r = 0; r < 4; ++r) {
        int m = blockIdx.x * 128 + wm * 64 + mi * 16 + lk * 4 + r;
        int n = blockIdx.y * 128 + wn * 64 + nj * 16 + lm;
        size_t idx = (size_t)m * 1024 + n;
        out[idx] = acc[mi][nj][r] + b2[n] + x[idx];
      }
}

// ---------- fused attention, 32x32-MFMA path, 64 q-rows per wave (straight-line) ----------
// scores = QK^T/8 + tril(1.0), softmax over FULL row (log2 domain), ctx = P*V.
// 4 waves (256 thr), QBLK=256: each wave owns 64 q rows as two named subtiles A/B of 32.
// K/V fragment reads shared across both subtiles (DS per work halved vs 32q/wave).
// ALL per-subtile state de-arrayed (sA0..sB1, accA0..accB1, pwA/pwB) -> no scratch spill.
__global__ __launch_bounds__(256, 1) void attn_k(const u16* __restrict__ Qh,
                                                 const u16* __restrict__ Kh,
                                                 const u16* __restrict__ Vh,
                                                 u16* __restrict__ ctx) {
  // XCD-chunked swizzle: 512 blocks / 8 XCDs = 64 contiguous work items (8 bh) per XCD.
  const int bl = blockIdx.x;
  const int wk = (bl & 7) * 64 + (bl >> 3);
  const int bh = wk >> 3, qt = wk & 7;
  const int tid = threadIdx.x, w = tid >> 6, l = tid & 63;
  const int ql = l & 31, h = l >> 5;
  __shared__ __align__(16) u16 Ks[2][4096];
  __shared__ __align__(16) u16 Vs[2][4096];

  const size_t base = (size_t)bh * 131072;
  const int qb = qt * 256 + w * 64;         // wave q-base (64-aligned)
  const int qA = qb + ql, qB = qb + 32 + ql;
  bfx8 qfA[4], qfB[4];
  {
    const u16* qp = Qh + base + (size_t)qA * 64 + 8 * h;
    qfA[0] = *(const bfx8*)(qp);      qfA[1] = *(const bfx8*)(qp + 16);
    qfA[2] = *(const bfx8*)(qp + 32); qfA[3] = *(const bfx8*)(qp + 48);
    const u16* qp2 = Qh + base + (size_t)qB * 64 + 8 * h;
    qfB[0] = *(const bfx8*)(qp2);      qfB[1] = *(const bfx8*)(qp2 + 16);
    qfB[2] = *(const bfx8*)(qp2 + 32); qfB[3] = *(const bfx8*)(qp2 + 48);
  }
  float mA = -1024.f, mB = -1024.f, lA = 0.f, lB = 0.f;
  fx16 accA0 = 0.f, accA1 = 0.f, accB0 = 0.f, accB1 = 0.f;

  const char* Kg = (const char*)(Kh + base);
  const char* Vg = (const char*)(Vh + base);
  const int o = tid * 16;
  const int sw8 = (ql & 7) << 4;

#define STAGE(t, s)                                                        \
  {                                                                        \
    gload16(Kg + (size_t)(t) * 8192 + o,        (char*)Ks[s] + o);         \
    gload16(Kg + (size_t)(t) * 8192 + o + 4096, (char*)Ks[s] + o + 4096);  \
    gload16(Vg + (size_t)(t) * 8192 + o,        (char*)Vs[s] + o);         \
    gload16(Vg + (size_t)(t) * 8192 + o + 4096, (char*)Vs[s] + o + 4096);  \
  }

  STAGE(0, 0);
  asm volatile("s_waitcnt vmcnt(0)" ::: "memory");
  __builtin_amdgcn_s_barrier();
  __builtin_amdgcn_sched_barrier(0);

  int cur = 0;
  for (int kt = 0; kt < 32; ++kt) {
    if (kt + 1 < 32) STAGE(kt + 1, cur ^ 1);
    __builtin_amdgcn_sched_barrier(0);

    const char* Kc = (const char*)Ks[cur];
    const char* Vc = (const char*)Vs[cur];

    // QK^T (swapped): K-frags read ONCE, feed both subtiles
    fx16 sA0 = 0.f, sA1 = 0.f, sB0 = 0.f, sB1 = 0.f;
    __builtin_amdgcn_s_setprio(1);
#pragma unroll
    for (int ks = 0; ks < 4; ++ks) {
      bfx8 kf0 = *(const bfx8*)(Kc + (0 * 32 + ql) * 128 + (((ks << 5) | (h << 4)) ^ sw8));
      bfx8 kf1 = *(const bfx8*)(Kc + (1 * 32 + ql) * 128 + (((ks << 5) | (h << 4)) ^ sw8));
      sA0 = __builtin_amdgcn_mfma_f32_32x32x16_bf16(kf0, qfA[ks], sA0, 0, 0, 0);
      sB0 = __builtin_amdgcn_mfma_f32_32x32x16_bf16(kf0, qfB[ks], sB0, 0, 0, 0);
      sA1 = __builtin_amdgcn_mfma_f32_32x32x16_bf16(kf1, qfA[ks], sA1, 0, 0, 0);
      sB1 = __builtin_amdgcn_mfma_f32_32x32x16_bf16(kf1, qfB[ks], sB1, 0, 0, 0);
    }
    __builtin_amdgcn_s_setprio(0);

    // softmax (log2 domain, bias-folded, joint defer-max ballot)
    const int dk = kt - (qb >> 6);          // qb 64-aligned -> same dk for A and B
    {
      float cO = -mA, cI = cO + MAc;
      mask_tile(sA0, dk, kt * 64 + 4 * h,      qA, cO, cI);
      mask_tile(sA1, dk, kt * 64 + 32 + 4 * h, qA, cO, cI);
    }
    {
      float cO = -mB, cI = cO + MAc;
      mask_tile(sB0, dk, kt * 64 + 4 * h,      qB, cO, cI);
      mask_tile(sB1, dk, kt * 64 + 32 + 4 * h, qB, cO, cI);
    }
    float mxA = vmax32(sA0, sA1);
    float mxB = vmax32(sB0, sB1);
    float fullA = fmaxf(mxA, __shfl_xor(mxA, 32));
    float fullB = fmaxf(mxB, __shfl_xor(mxB, 32));
    if (!__all(fmaxf(fullA, fullB) <= THRc)) {   // rare rescale (d=0 -> harmless no-op)
      float dA = fmaxf(fullA, 0.f), corrA = ex2(-dA);
      mA += dA; lA *= corrA;
      rescale32(accA0, accA1, sA0, sA1, dA, corrA, l, h);
      float dB = fmaxf(fullB, 0.f), corrB = ex2(-dB);
      mB += dB; lB *= corrB;
      rescale32(accB0, accB1, sB0, sB1, dB, corrB, l, h);
    }
    lA += expsum32(sA0, sA1);
    lB += expsum32(sB0, sB1);
    uint32_t pwA[8][2], pwB[8][2];
    pack32(sA0, sA1, pwA);
    pack32(sB0, sB1, pwB);

    // PV: V-frags read ONCE, feed both subtiles; pa via xor-32 exchange (round-8 verified)
    __builtin_amdgcn_s_setprio(1);
#pragma unroll
    for (int ks = 0; ks < 4; ++ks) {
      bfx8 vf0 = *(const bfx8*)(Vc + (0 * 32 + ql) * 128 + (((ks << 5) | (h << 4)) ^ sw8));
      bfx8 vf1 = *(const bfx8*)(Vc + (1 * 32 + ql) * 128 + (((ks << 5) | (h << 4)) ^ sw8));
      bfx8 paA = mk_pa(pwA, ks, h);
      bfx8 paB = mk_pa(pwB, ks, h);
      accA0 = __builtin_amdgcn_mfma_f32_32x32x16_bf16(paA, vf0, accA0, 0, 0, 0);
      accB0 = __builtin_amdgcn_mfma_f32_32x32x16_bf16(paB, vf0, accB0, 0, 0, 0);
      accA1 = __builtin_amdgcn_mfma_f32_32x32x16_bf16(paA, vf1, accA1, 0, 0, 0);
      accB1 = __builtin_amdgcn_mfma_f32_32x32x16_bf16(paB, vf1, accB1, 0, 0, 0);
    }
    __builtin_amdgcn_s_setprio(0);

    asm volatile("s_waitcnt vmcnt(0)" ::: "memory");   // next tile landed (in flight all iter)
    __builtin_amdgcn_s_barrier();
    __builtin_amdgcn_sched_barrier(0);
    cur ^= 1;
  }
#undef STAGE

  // epilogue: pair-reduce l, write ctx (B,S,D) bf16
  const int b = bh >> 4, hcol = bh & 15;
  {
    float inv = 1.0f / (lA + __shfl_xor(lA, 32));
#pragma unroll
    for (int r = 0; r < 16; ++r) {
      int rq = (r & 3) + 8 * (r >> 2) + 4 * h;
      float invq = __shfl(inv, (l & 32) | rq);
      size_t rowb = ((size_t)b * 2048 + (qb + rq)) * 1024 + hcol * 64 + ql;
      ctx[rowb]      = f2b(accA0[r] * invq);
      ctx[rowb + 32] = f2b(accA1[r] * invq);
    }
  }
  {
    float inv = 1.0f / (lB + __shfl_xor(lB, 32));
#pragma unroll
    for (int r = 0; r < 16; ++r) {
      int rq = (r & 3) + 8 * (r >> 2) + 4 * h;
      float invq = __shfl(inv, (l & 32) | rq);
      size_t rowb = ((size_t)b * 2048 + (qb + 32 + rq)) * 1024 + hcol * 64 + ql;
      ctx[rowb]      = f2b(accB0[r] * invq);
      ctx[rowb + 32] = f2b(accB1[r] * invq);
    }
  }
}

// ---------- launch ----------
extern "C" void kernel_launch(void* const* d_in, const int* in_sizes, int n_in,
                              void* d_out, int out_size, void* d_ws, size_t ws_size,
                              hipStream_t stream) {
  (void)in_sizes; (void)n_in; (void)out_size; (void)ws_size;
  const float* x      = (const float*)d_in[0];
  const float* Wq     = (const float*)d_in[1];
  const float* Wk     = (const float*)d_in[2];
  const float* Wv     = (const float*)d_in[3];
  const float* in_w   = (const float*)d_in[4];
  const float* in_b   = (const float*)d_in[5];
  const float* out_w  = (const float*)d_in[6];
  const float* out_b  = (const float*)d_in[7];
  const float* proj_w = (const float*)d_in[8];
  const float* proj_b = (const float*)d_in[9];
  float* out = (float*)d_out;

  char* ws = (char*)d_ws;
  const size_t MB = 1ull << 20;
  // lifetime-overlapped layout (72 MB + 4 KB total):
  u16* xb   = (u16*)(ws);                    // 16MB; dead after QKV GEMM -> reused as ctx
  u16* ctx  = xb;
  u16* Qh   = (u16*)(ws + 16 * MB);          // 16MB
  u16* Kh   = (u16*)(ws + 32 * MB);          // 16MB; first 6MB doubles as in_w bf16 (prep only)
  u16* Vh   = (u16*)(ws + 48 * MB);          // 16MB; first 8MB = tmpT, +2MB = proj_w bf16 (prep only)
  u16* inwb = Kh;
  u16* tmpT = Vh;
  u16* pwb  = (u16*)(ws + 48 * MB + 8 * MB);
  u16* Wc   = (u16*)(ws + 64 * MB);          // 6MB combined QKV weights
  u16* W2   = (u16*)(ws + 70 * MB);          // 2MB combined output weights
  float* b2 = (float*)(ws + 72 * MB);        // 4KB combined output bias

  f32_to_bf16_k<<<4096, 256, 0, stream>>>(x, xb, 8388608);
  f32_to_bf16_k<<<1536, 256, 0, stream>>>(in_w, inwb, 3145728);
  f32_to_bf16_k<<<512, 256, 0, stream>>>(proj_w, pwb, 1048576);

  TransArgs ta;
  ta.in[0] = Wq; ta.in[1] = Wk; ta.in[2] = Wv; ta.in[3] = out_w;
  for (int z = 0; z < 4; ++z) ta.out[z] = tmpT + (size_t)z * 1048576;
  transpose4_k<<<dim3(16, 16, 4), 256, 0, stream>>>(ta);

  CombArgs ca;
  ca.A[0] = inwb; ca.A[1] = inwb + 1048576; ca.A[2] = inwb + 2097152; ca.A[3] = pwb;
  for (int z = 0; z < 4; ++z) ca.Bt[z] = tmpT + (size_t)z * 1048576;
  ca.C[0] = Wc; ca.C[1] = Wc + 1048576; ca.C[2] = Wc + 2097152; ca.C[3] = W2;
  gemm_combine_k<<<dim3(8, 8, 4), 256, 0, stream>>>(ca);

  make_b2_k<<<1024, 256, 0, stream>>>(proj_w, out_b, proj_b, b2);

  gemm_qkv_k<<<dim3(64, 24), 256, 0, stream>>>(xb, Wc, in_b, Qh, Kh, Vh);
  attn_k<<<512, 256, 0, stream>>>(Qh, Kh, Vh, ctx);
  gemm_final_k<<<dim3(64, 8), 256, 0, stream>>>(ctx, W2, b2, x, out);
}

// Round 11
// 266.230 us; speedup vs baseline: 1.2234x; 1.1899x over previous
//
#include <hip/hip_runtime.h>
#include <stdint.h>

typedef unsigned short u16;
typedef __attribute__((ext_vector_type(8))) short bfx8;   // 8 bf16 = 4 VGPR (MFMA A/B frag)
typedef __attribute__((ext_vector_type(4))) float fx4;    // 16x16 MFMA C/D frag
typedef __attribute__((ext_vector_type(16))) float fx16;  // 32x32 MFMA C/D frag

// ---------- helpers ----------
static __device__ __forceinline__ u16 f2b(float f) {
  union { float f; uint32_t u; } v; v.f = f;
  uint32_t r = v.u + 0x7fffu + ((v.u >> 16) & 1u);   // RNE
  return (u16)(r >> 16);
}

static __device__ __forceinline__ uint32_t cvtpk(float lo, float hi) {
  uint32_t r;
  asm("v_cvt_pk_bf16_f32 %0, %1, %2" : "=v"(r) : "v"(lo), "v"(hi));
  return r;
}

static __device__ __forceinline__ float ex2(float x) {   // raw v_exp_f32 (2^x)
  float r;
  asm("v_exp_f32 %0, %1" : "=v"(r) : "v"(x));
  return r;
}

static __device__ __forceinline__ void gload16(const void* g, void* lds) {
  __builtin_amdgcn_global_load_lds((const __attribute__((address_space(1))) uint32_t*)g,
                                   (__attribute__((address_space(3))) uint32_t*)lds,
                                   16, 0, 0);
}

// ---------- f32 -> bf16 convert (8 elems/thread, vectorized) ----------
__global__ __launch_bounds__(256) void f32_to_bf16_k(const float* __restrict__ in,
                                                     u16* __restrict__ out, int n) {
  int i = (blockIdx.x * 256 + threadIdx.x) * 8;
  if (i >= n) return;
  float4 a = *(const float4*)(in + i);
  float4 b = *(const float4*)(in + i + 4);
  bfx8 o;
  o[0]=(short)f2b(a.x); o[1]=(short)f2b(a.y); o[2]=(short)f2b(a.z); o[3]=(short)f2b(a.w);
  o[4]=(short)f2b(b.x); o[5]=(short)f2b(b.y); o[6]=(short)f2b(b.z); o[7]=(short)f2b(b.w);
  *(bfx8*)(out + i) = o;
}

// ---------- 1024x1024 f32 transpose -> bf16 (4 matrices batched in z) ----------
struct TransArgs { const float* in[4]; u16* out[4]; };
__global__ __launch_bounds__(256) void transpose4_k(TransArgs ta) {
  const float* in = ta.in[blockIdx.z];
  u16* out = ta.out[blockIdx.z];
  __shared__ u16 t[64][65];
  const int bx = blockIdx.x * 64, by = blockIdx.y * 64;
  const int tid = threadIdx.x;
#pragma unroll
  for (int i = 0; i < 16; ++i) {
    int idx = tid + i * 256; int r = idx >> 6, c = idx & 63;
    t[c][r] = f2b(in[(size_t)(by + r) * 1024 + bx + c]);
  }
  __syncthreads();
#pragma unroll
  for (int i = 0; i < 16; ++i) {
    int idx = tid + i * 256; int r = idx >> 6, c = idx & 63;
    out[(size_t)(bx + r) * 1024 + by + c] = t[r][c];
  }
}

// ---------- b2[f] = proj_b[f] + sum_e proj_w[f][e]*out_b[e] ----------
__global__ __launch_bounds__(256) void make_b2_k(const float* __restrict__ pw,
                                                 const float* __restrict__ ob,
                                                 const float* __restrict__ pb,
                                                 float* __restrict__ b2) {
  const int f = blockIdx.x, tid = threadIdx.x;
  float s = 0.f;
  for (int e = tid; e < 1024; e += 256) s += pw[(size_t)f * 1024 + e] * ob[e];
#pragma unroll
  for (int d = 1; d < 64; d <<= 1) s += __shfl_xor(s, d);
  __shared__ float red[4];
  if ((tid & 63) == 0) red[tid >> 6] = s;
  __syncthreads();
  if (tid == 0) b2[f] = red[0] + red[1] + red[2] + red[3] + pb[f];
}

// ---------- GEMM core: C = A(MxK) * Bt(NxK)^T, 128x128 tile, BK=64, 4 waves ----------
static __device__ __forceinline__ void gemm_core(const u16* __restrict__ A,
                                                 const u16* __restrict__ Bt,
                                                 int K, int bm, int bn,
                                                 u16* As, u16* Bs, fx4 (&acc)[4][4]) {
  const int tid = threadIdx.x, w = tid >> 6, l = tid & 63, lm = l & 15, lk = l >> 4;
  const int wm = w >> 1, wn = w & 1;
  const int nkt = K >> 6;
  for (int kt = 0; kt < nkt; ++kt) {
#pragma unroll
    for (int i = 0; i < 4; ++i) {
      int off = i * 4096 + w * 1024;         // wave-uniform LDS byte base
      int loff = off + l * 16;               // this lane's byte
      int row = loff >> 7, cb = loff & 127;  // tile row, byte-in-row (BK*2=128B rows)
      gload16((const char*)A + ((size_t)(bm * 128 + row) * K + kt * 64) * 2 + cb,
              (char*)As + off);
      gload16((const char*)Bt + ((size_t)(bn * 128 + row) * K + kt * 64) * 2 + cb,
              (char*)Bs + off);
    }
    __syncthreads();
#pragma unroll
    for (int kk = 0; kk < 2; ++kk) {
      bfx8 a[4], b[4];
#pragma unroll
      for (int mi = 0; mi < 4; ++mi)
        a[mi] = *(const bfx8*)((const char*)As + (wm * 64 + mi * 16 + lm) * 128 + lk * 16 + kk * 64);
#pragma unroll
      for (int nj = 0; nj < 4; ++nj)
        b[nj] = *(const bfx8*)((const char*)Bs + (wn * 64 + nj * 16 + lm) * 128 + lk * 16 + kk * 64);
#pragma unroll
      for (int mi = 0; mi < 4; ++mi)
#pragma unroll
        for (int nj = 0; nj < 4; ++nj)
          acc[mi][nj] = __builtin_amdgcn_mfma_f32_16x16x32_bf16(a[mi], b[nj], acc[mi][nj], 0, 0, 0);
    }
    __syncthreads();
  }
}

// ---------- combine GEMMs (4 batched in z): C[f][d] = sum_e A[f][e]*Bt[d][e], bf16 out ----------
struct CombArgs { const u16* A[4]; const u16* Bt[4]; u16* C[4]; };
__global__ __launch_bounds__(256) void gemm_combine_k(CombArgs ca) {
  const int z = blockIdx.z;
  __shared__ u16 As[8192], Bs[8192];
  fx4 acc[4][4];
#pragma unroll
  for (int mi = 0; mi < 4; ++mi)
#pragma unroll
    for (int nj = 0; nj < 4; ++nj) acc[mi][nj] = 0.f;
  gemm_core(ca.A[z], ca.Bt[z], 1024, blockIdx.x, blockIdx.y, As, Bs, acc);
  const int tid = threadIdx.x, w = tid >> 6, l = tid & 63, lm = l & 15, lk = l >> 4;
  const int wm = w >> 1, wn = w & 1;
  u16* C = ca.C[z];
#pragma unroll
  for (int mi = 0; mi < 4; ++mi)
#pragma unroll
    for (int nj = 0; nj < 4; ++nj)
#pragma unroll
      for (int r = 0; r < 4; ++r) {
        int m = blockIdx.x * 128 + wm * 64 + mi * 16 + lk * 4 + r;
        int n = blockIdx.y * 128 + wn * 64 + nj * 16 + lm;
        C[(size_t)m * 1024 + n] = f2b(acc[mi][nj][r]);
      }
}

// ---------- QKV GEMM: [8192x1024]x[3072x1024]^T + in_b, XCD-chunked grid ----------
// grid = 1536 flat blocks; XCD j owns bm in [8j, 8j+8) for all bn -> its 2MB A-panel
// stays L2-resident. Q -> (B,H,S,64) plain; K -> hd XOR-swizzled; V -> transposed
// per-64-tile Vt[d][k], row-XOR-swizzled.
__global__ __launch_bounds__(256) void gemm_qkv_k(const u16* __restrict__ xb,
                                                  const u16* __restrict__ Wc,
                                                  const float* __restrict__ bias,
                                                  u16* __restrict__ Qh, u16* __restrict__ Kh,
                                                  u16* __restrict__ Vh) {
  const int bl = blockIdx.x;
  const int xcd = bl & 7, local = bl >> 3;        // local 0..191
  const int bm = xcd * 8 + (local & 7);           // 0..63
  const int bn = local >> 3;                      // 0..23
  __shared__ u16 As[8192], Bs[8192];
  fx4 acc[4][4];
#pragma unroll
  for (int mi = 0; mi < 4; ++mi)
#pragma unroll
    for (int nj = 0; nj < 4; ++nj) acc[mi][nj] = 0.f;
  gemm_core(xb, Wc, 1024, bm, bn, As, Bs, acc);
  const int tid = threadIdx.x, w = tid >> 6, l = tid & 63, lm = l & 15, lk = l >> 4;
  const int wm = w >> 1, wn = w & 1;
  const int t = bn >> 3;                          // tensor select (tile-uniform)
  u16* dst = (t == 0) ? Qh : ((t == 1) ? Kh : Vh);
#pragma unroll
  for (int mi = 0; mi < 4; ++mi)
#pragma unroll
    for (int nj = 0; nj < 4; ++nj)
#pragma unroll
      for (int r = 0; r < 4; ++r) {
        int m = bm * 128 + wm * 64 + mi * 16 + lk * 4 + r;
        int n = bn * 128 + wn * 64 + nj * 16 + lm;
        float v = acc[mi][nj][r] + bias[n];
        int f = n & 1023, h = f >> 6, hd = f & 63, b = m >> 11, s = m & 2047;
        size_t hb = ((size_t)(b * 16 + h)) * 131072;   // 2048*64
        size_t idx;
        if (t == 2) {
          int sl = s & 63, st = s >> 6;                // Vt[d=hd][k=sl], row-swizzled
          idx = hb + (size_t)st * 4096 + (size_t)(hd * 64 + (sl ^ ((hd & 7) << 3)));
        } else if (t == 1) {
          idx = hb + (size_t)s * 64 + (hd ^ ((s & 7) << 3));
        } else {
          idx = hb + (size_t)s * 64 + hd;
        }
        dst[idx] = f2b(v);
      }
}

// ---------- final GEMM: ctx[8192x1024] x W2[1024x1024]^T + b2 + x, f32 out ----------
// XCD-chunked grid: 512 flat blocks; XCD j owns bm in [8j, 8j+8).
__global__ __launch_bounds__(256) void gemm_final_k(const u16* __restrict__ ctx,
                                                    const u16* __restrict__ W2,
                                                    const float* __restrict__ b2,
                                                    const float* __restrict__ x,
                                                    float* __restrict__ out) {
  const int bl = blockIdx.x;
  const int xcd = bl & 7, local = bl >> 3;        // local 0..63
  const int bm = xcd * 8 + (local & 7);           // 0..63
  const int bn = local >> 3;                      // 0..7
  __shared__ u16 As[8192], Bs[8192];
  fx4 acc[4][4];
#pragma unroll
  for (int mi = 0; mi < 4; ++mi)
#pragma unroll
    for (int nj = 0; nj < 4; ++nj) acc[mi][nj] = 0.f;
  gemm_core(ctx, W2, 1024, bm, bn, As, Bs, acc);
  const int tid = threadIdx.x, w = tid >> 6, l = tid & 63, lm = l & 15, lk = l >> 4;
  const int wm = w >> 1, wn = w & 1;
#pragma unroll
  for (int mi = 0; mi < 4; ++mi)
#pragma unroll
    for (int nj = 0; nj < 4; ++nj)
#pragma unroll
      for (int r = 0; r < 4; ++r) {
        int m = bm * 128 + wm * 64 + mi * 16 + lk * 4 + r;
        int n = bn * 128 + wn * 64 + nj * 16 + lm;
        size_t idx = (size_t)m * 1024 + n;
        out[idx] = acc[mi][nj][r] + b2[n] + x[idx];
      }
}

// ---------- fused attention, 32x32-MFMA path (round-8 per-wave code, 8-wave blocks) ----------
// scores = QK^T/8 + tril(1.0), softmax over FULL row (log2 domain), ctx = P*V.
// 8 waves (512 thr), QBLK=256: each wave owns 32 q rows; lane owns q = qb + (l&31),
// key-half h = l>>5. K/V tile (16KB) staged ONCE per block, shared by 8 waves.
// 64 VGPR/wave -> 4 blocks/CU = 32 waves/CU for latency hiding.
__global__ __launch_bounds__(512, 4) void attn_k(const u16* __restrict__ Qh,
                                                 const u16* __restrict__ Kh,
                                                 const u16* __restrict__ Vh,
                                                 u16* __restrict__ ctx) {
  // XCD-chunked swizzle: 512 blocks / 8 XCDs = 64 contiguous work items (8 bh) per XCD.
  const int bl = blockIdx.x;
  const int wk = (bl & 7) * 64 + (bl >> 3);
  const int bh = wk >> 3, qt = wk & 7;
  const int tid = threadIdx.x, w = tid >> 6, l = tid & 63;
  const int ql = l & 31, h = l >> 5;
  __shared__ __align__(16) u16 Ks[2][4096];
  __shared__ __align__(16) u16 Vs[2][4096];

  const float SC = 0.18033688011112042f;    // 0.125 * log2(e)
  const float MA = 1.4426950408889634f;     // 1.0  * log2(e)
  const float THR = 11.541560327111708f;    // 8.0  * log2(e)

  const size_t base = (size_t)bh * 131072;
  const int qb = qt * 256 + w * 32;         // wave q-base (32-aligned; dk logic handles it)
  const int q = qb + ql;                    // lane's q row
  bfx8 qf[4];
  {
    const u16* qp = Qh + base + (size_t)q * 64 + 8 * h;
    qf[0] = *(const bfx8*)(qp);
    qf[1] = *(const bfx8*)(qp + 16);
    qf[2] = *(const bfx8*)(qp + 32);
    qf[3] = *(const bfx8*)(qp + 48);
  }
  float m_run = -1024.f, l_part = 0.f;
  fx16 accO[2];
  accO[0] = 0.f; accO[1] = 0.f;

  const char* Kg = (const char*)(Kh + base);
  const char* Vg = (const char*)(Vh + base);
  const int o = tid * 16;                   // 512 thr x 16B = full 8KB tile per instr
  const int sw8 = (ql & 7) << 4;

#define STAGE(t, s)                                            \
  {                                                            \
    gload16(Kg + (size_t)(t) * 8192 + o, (char*)Ks[s] + o);    \
    gload16(Vg + (size_t)(t) * 8192 + o, (char*)Vs[s] + o);    \
  }

  STAGE(0, 0);
  asm volatile("s_waitcnt vmcnt(0)" ::: "memory");
  __builtin_amdgcn_s_barrier();
  __builtin_amdgcn_sched_barrier(0);

  int cur = 0;
  for (int kt = 0; kt < 32; ++kt) {
    if (kt + 1 < 32) STAGE(kt + 1, cur ^ 1);   // issue early; lands before end-of-iter wait
    __builtin_amdgcn_sched_barrier(0);

    const char* Kc = (const char*)Ks[cur];
    const char* Vc = (const char*)Vs[cur];

    // QK^T (swapped): S[q][key]; lane col = ql, key rows = kb*32 + (r&3)+8*(r>>2)+4h
    fx16 sS[2];
    sS[0] = 0.f; sS[1] = 0.f;
    __builtin_amdgcn_s_setprio(1);
#pragma unroll
    for (int ks = 0; ks < 4; ++ks) {
      bfx8 kf0 = *(const bfx8*)(Kc + (0 * 32 + ql) * 128 + (((ks << 5) | (h << 4)) ^ sw8));
      bfx8 kf1 = *(const bfx8*)(Kc + (1 * 32 + ql) * 128 + (((ks << 5) | (h << 4)) ^ sw8));
      sS[0] = __builtin_amdgcn_mfma_f32_32x32x16_bf16(kf0, qf[ks], sS[0], 0, 0, 0);
      sS[1] = __builtin_amdgcn_mfma_f32_32x32x16_bf16(kf1, qf[ks], sS[1], 0, 0, 0);
    }
    __builtin_amdgcn_s_setprio(0);

    // scale to log2 domain + additive tril mask, bias-folded (cO = -m_run)
    const int dk = kt - (qb >> 6);
    {
      float cO = -m_run, cI = cO + MA;
      if (dk < 0) {
#pragma unroll
        for (int r = 0; r < 16; ++r) {
          sS[0][r] = fmaf(sS[0][r], SC, cI);
          sS[1][r] = fmaf(sS[1][r], SC, cI);
        }
      } else if (dk > 0) {
#pragma unroll
        for (int r = 0; r < 16; ++r) {
          sS[0][r] = fmaf(sS[0][r], SC, cO);
          sS[1][r] = fmaf(sS[1][r], SC, cO);
        }
      } else {
#pragma unroll
        for (int kb = 0; kb < 2; ++kb)
#pragma unroll
          for (int r = 0; r < 16; ++r) {
            int key = kt * 64 + kb * 32 + (r & 3) + 8 * (r >> 2) + 4 * h;
            sS[kb][r] = fmaf(sS[kb][r], SC, (key <= q) ? cI : cO);
          }
      }
    }
    // local max over this lane's 32 scores; row-combine with the partner half lane
    float mx;
    {
      float m0 = fmaxf(fmaxf(sS[0][0], sS[0][1]), fmaxf(sS[0][2], sS[0][3]));
      float m1 = fmaxf(fmaxf(sS[0][4], sS[0][5]), fmaxf(sS[0][6], sS[0][7]));
      float m2 = fmaxf(fmaxf(sS[0][8], sS[0][9]), fmaxf(sS[0][10], sS[0][11]));
      float m3 = fmaxf(fmaxf(sS[0][12], sS[0][13]), fmaxf(sS[0][14], sS[0][15]));
      float m4 = fmaxf(fmaxf(sS[1][0], sS[1][1]), fmaxf(sS[1][2], sS[1][3]));
      float m5 = fmaxf(fmaxf(sS[1][4], sS[1][5]), fmaxf(sS[1][6], sS[1][7]));
      float m6 = fmaxf(fmaxf(sS[1][8], sS[1][9]), fmaxf(sS[1][10], sS[1][11]));
      float m7 = fmaxf(fmaxf(sS[1][12], sS[1][13]), fmaxf(sS[1][14], sS[1][15]));
      mx = fmaxf(fmaxf(fmaxf(m0, m1), fmaxf(m2, m3)), fmaxf(fmaxf(m4, m5), fmaxf(m6, m7)));
    }
    float full = fmaxf(mx, __shfl_xor(mx, 32));   // row max over this tile's 64 keys
    if (!__all(full <= THR)) {                    // rare rescale (defer-max)
      float d = fmaxf(full, 0.f);
      float corr = ex2(-d);
      m_run += d;
      l_part *= corr;
#pragma unroll
      for (int r = 0; r < 16; ++r) {
        int rq = (r & 3) + 8 * (r >> 2) + 4 * h;
        float cr = __shfl(corr, (l & 32) | rq);
        accO[0][r] *= cr;
        accO[1][r] *= cr;
        sS[0][r] -= d;
        sS[1][r] -= d;
      }
    }
    // exp + partial row-sum (this half only; pair-reduced in epilogue)
    fx16 tt;
#pragma unroll
    for (int r = 0; r < 16; ++r) {
      sS[0][r] = ex2(sS[0][r]);
      sS[1][r] = ex2(sS[1][r]);
      tt[r] = sS[0][r] + sS[1][r];
    }
    {
      float ls0 = tt[0] + tt[8],  ls1 = tt[1] + tt[9];
      float ls2 = tt[2] + tt[10], ls3 = tt[3] + tt[11];
      float ls4 = tt[4] + tt[12], ls5 = tt[5] + tt[13];
      float ls6 = tt[6] + tt[14], ls7 = tt[7] + tt[15];
      l_part += ((ls0 + ls4) + (ls1 + ls5)) + ((ls2 + ls6) + (ls3 + ls7));
    }
    // P -> PV A-frags: cvt_pk pairs, then xor-32 exchange (round-8 verified).
    uint32_t pw[8][2];
#pragma unroll
    for (int kb = 0; kb < 2; ++kb)
#pragma unroll
      for (int gg = 0; gg < 4; ++gg) {
        pw[kb * 4 + gg][0] = cvtpk(sS[kb][4 * gg + 0], sS[kb][4 * gg + 1]);
        pw[kb * 4 + gg][1] = cvtpk(sS[kb][4 * gg + 2], sS[kb][4 * gg + 3]);
      }

    // PV: O[q][d] += P[q][k] V[k][d]; B-frag from transposed V tile (plain b128)
    __builtin_amdgcn_s_setprio(1);
#pragma unroll
    for (int ks = 0; ks < 4; ++ks) {
      union { uint32_t u[4]; bfx8 v; } pa;
#pragma unroll
      for (int p = 0; p < 2; ++p) {
        uint32_t contrib = h ? pw[2 * ks][p] : pw[2 * ks + 1][p];
        uint32_t rcv = __shfl_xor(contrib, 32);
        pa.u[p]     = h ? rcv : pw[2 * ks][p];       // keys 16ks+8h+{0..3}
        pa.u[2 + p] = h ? pw[2 * ks + 1][p] : rcv;   // keys 16ks+8h+{4..7}
      }
      bfx8 vf0 = *(const bfx8*)(Vc + (0 * 32 + ql) * 128 + (((ks << 5) | (h << 4)) ^ sw8));
      bfx8 vf1 = *(const bfx8*)(Vc + (1 * 32 + ql) * 128 + (((ks << 5) | (h << 4)) ^ sw8));
      accO[0] = __builtin_amdgcn_mfma_f32_32x32x16_bf16(pa.v, vf0, accO[0], 0, 0, 0);
      accO[1] = __builtin_amdgcn_mfma_f32_32x32x16_bf16(pa.v, vf1, accO[1], 0, 0, 0);
    }
    __builtin_amdgcn_s_setprio(0);

    asm volatile("s_waitcnt vmcnt(0)" ::: "memory");   // next tile landed (in flight all iter)
    __builtin_amdgcn_s_barrier();
    __builtin_amdgcn_sched_barrier(0);
    cur ^= 1;
  }
#undef STAGE

  // epilogue: pair-reduce l, write ctx (B,S,D) bf16
  float inv = 1.0f / (l_part + __shfl_xor(l_part, 32));   // full row sum for q
  const int b = bh >> 4, hcol = bh & 15;
#pragma unroll
  for (int r = 0; r < 16; ++r) {
    int rq = (r & 3) + 8 * (r >> 2) + 4 * h;
    float invq = __shfl(inv, (l & 32) | rq);
    size_t rowb = ((size_t)b * 2048 + (qb + rq)) * 1024 + hcol * 64 + ql;
    ctx[rowb]      = f2b(accO[0][r] * invq);   // d = ql
    ctx[rowb + 32] = f2b(accO[1][r] * invq);   // d = 32 + ql
  }
}

// ---------- launch ----------
extern "C" void kernel_launch(void* const* d_in, const int* in_sizes, int n_in,
                              void* d_out, int out_size, void* d_ws, size_t ws_size,
                              hipStream_t stream) {
  (void)in_sizes; (void)n_in; (void)out_size; (void)ws_size;
  const float* x      = (const float*)d_in[0];
  const float* Wq     = (const float*)d_in[1];
  const float* Wk     = (const float*)d_in[2];
  const float* Wv     = (const float*)d_in[3];
  const float* in_w   = (const float*)d_in[4];
  const float* in_b   = (const float*)d_in[5];
  const float* out_w  = (const float*)d_in[6];
  const float* out_b  = (const float*)d_in[7];
  const float* proj_w = (const float*)d_in[8];
  const float* proj_b = (const float*)d_in[9];
  float* out = (float*)d_out;

  char* ws = (char*)d_ws;
  const size_t MB = 1ull << 20;
  // lifetime-overlapped layout (72 MB + 4 KB total):
  u16* xb   = (u16*)(ws);                    // 16MB; dead after QKV GEMM -> reused as ctx
  u16* ctx  = xb;
  u16* Qh   = (u16*)(ws + 16 * MB);          // 16MB
  u16* Kh   = (u16*)(ws + 32 * MB);          // 16MB; first 6MB doubles as in_w bf16 (prep only)
  u16* Vh   = (u16*)(ws + 48 * MB);          // 16MB; first 8MB = tmpT, +2MB = proj_w bf16 (prep only)
  u16* inwb = Kh;
  u16* tmpT = Vh;
  u16* pwb  = (u16*)(ws + 48 * MB + 8 * MB);
  u16* Wc   = (u16*)(ws + 64 * MB);          // 6MB combined QKV weights
  u16* W2   = (u16*)(ws + 70 * MB);          // 2MB combined output weights
  float* b2 = (float*)(ws + 72 * MB);        // 4KB combined output bias

  f32_to_bf16_k<<<4096, 256, 0, stream>>>(x, xb, 8388608);
  f32_to_bf16_k<<<1536, 256, 0, stream>>>(in_w, inwb, 3145728);
  f32_to_bf16_k<<<512, 256, 0, stream>>>(proj_w, pwb, 1048576);

  TransArgs ta;
  ta.in[0] = Wq; ta.in[1] = Wk; ta.in[2] = Wv; ta.in[3] = out_w;
  for (int z = 0; z < 4; ++z) ta.out[z] = tmpT + (size_t)z * 1048576;
  transpose4_k<<<dim3(16, 16, 4), 256, 0, stream>>>(ta);

  CombArgs ca;
  ca.A[0] = inwb; ca.A[1] = inwb + 1048576; ca.A[2] = inwb + 2097152; ca.A[3] = pwb;
  for (int z = 0; z < 4; ++z) ca.Bt[z] = tmpT + (size_t)z * 1048576;
  ca.C[0] = Wc; ca.C[1] = Wc + 1048576; ca.C[2] = Wc + 2097152; ca.C[3] = W2;
  gemm_combine_k<<<dim3(8, 8, 4), 256, 0, stream>>>(ca);

  make_b2_k<<<1024, 256, 0, stream>>>(proj_w, out_b, proj_b, b2);

  gemm_qkv_k<<<1536, 256, 0, stream>>>(xb, Wc, in_b, Qh, Kh, Vh);
  attn_k<<<512, 512, 0, stream>>>(Qh, Kh, Vh, ctx);
  gemm_final_k<<<512, 256, 0, stream>>>(ctx, W2, b2, x, out);
}